// Round 1
// 3847.811 us; speedup vs baseline: 1.4661x; 1.4661x over previous
//
#include <hip/hip_runtime.h>

typedef unsigned short u16;
typedef unsigned int u32;
typedef __bf16 bf16;
typedef bf16 bf16x8 __attribute__((ext_vector_type(8)));
typedef u16 u16x8 __attribute__((ext_vector_type(8)));
typedef float f32x4 __attribute__((ext_vector_type(4)));

#define DEV static __device__ __forceinline__

DEV u16 f2bf(float f) { return __builtin_bit_cast(u16, (bf16)f); }
DEV u32 pack2(float a, float b) { return (u32)f2bf(a) | ((u32)f2bf(b) << 16); }
DEV float bf2f(u16 u) { u32 v = ((u32)u) << 16; return __builtin_bit_cast(float, v); }
DEV bf16x8 frag_ld(const u16* p) { return __builtin_bit_cast(bf16x8, *(const u16x8*)p); }

#define MFMA(a, b, c) __builtin_amdgcn_mfma_f32_16x16x32_bf16(a, b, c, 0, 0, 0)

// ---------------------------------------------------------------- embed gather
__global__ __launch_bounds__(256) void embed_k(const int* __restrict__ tok,
                                               const float* __restrict__ E,
                                               float* __restrict__ Y) {
  int row = blockIdx.x, t = threadIdx.x;
  int tk = tok[row];
  *(float4*)&Y[(size_t)row * 1024 + t * 4] =
      *(const float4*)&E[(size_t)tk * 1024 + t * 4];
}

// ---------------------------------------------------------------- rmsnorm -> bf16
__global__ __launch_bounds__(256) void rmsnorm_k(const float* __restrict__ X,
                                                 const float* __restrict__ Sc,
                                                 u16* __restrict__ Out) {
  int row = blockIdx.x, t = threadIdx.x;
  const float4 xv = *(const float4*)&X[(size_t)row * 1024 + t * 4];
  float ss = xv.x * xv.x + xv.y * xv.y + xv.z * xv.z + xv.w * xv.w;
#pragma unroll
  for (int off = 32; off > 0; off >>= 1) ss += __shfl_down(ss, off);
  __shared__ float red[4];
  if ((t & 63) == 0) red[t >> 6] = ss;
  __syncthreads();
  float tot = red[0] + red[1] + red[2] + red[3];
  float r = rsqrtf(tot * (1.0f / 1024.0f) + 1e-6f);
  const float4 sv = *(const float4*)&Sc[t * 4];
  uint2 u;
  u.x = pack2(xv.x * r * sv.x, xv.y * r * sv.y);
  u.y = pack2(xv.z * r * sv.z, xv.w * r * sv.w);
  *(uint2*)&Out[(size_t)row * 1024 + t * 4] = u;
}

// ---------------------------------------------------------------- GEMM
// A bf16 [M][K], B fp32 [K][N] (converted to bf16 in staging), 128x128 tile, BK=32.
// Grid: x = m-tiles (16), y = n-tiles  -> consecutive blocks share the B panel
// (weight stays L2/LLC resident; B read ~once from HBM).
// EPI: 0 = write fp32 (LDS-coalesced float4 rows), 1 = write bf16 (z selects B/C),
//      2 = fp32 atomicAdd, z splits K in halves (2x blocks for skinny GEMMs)
template <int EPI>
__global__ __launch_bounds__(256) void gemm_k(
    const u16* __restrict__ A, const float* __restrict__ B0,
    const float* __restrict__ B1, const float* __restrict__ B2,
    void* __restrict__ C0, void* __restrict__ C1, void* __restrict__ C2,
    int M, int N, int K) {
  const float* B = B0;
  void* Cv = C0;
  int k_lo = 0, k_hi = K;
  if (EPI == 1) {
    if (blockIdx.z == 1) { B = B1; Cv = C1; }
    if (blockIdx.z == 2) { B = B2; Cv = C2; }
  }
  if (EPI == 2) {
    k_lo = blockIdx.z * (K >> 1);
    k_hi = k_lo + (K >> 1);
  }
  const int m0 = blockIdx.x * 128, n0 = blockIdx.y * 128;
  __shared__ uint4 smem4[20480 / 16];
  u16* As = (u16*)smem4;                    // [128][40] row-major (k-minor)
  u16* Bs = (u16*)smem4 + 5120;             // [128][40] k-chunk XOR-swizzled
  const int t = threadIdx.x;
  const int lane = t & 63, w = t >> 6;
  const int lr = lane & 15, lg = lane >> 4;
  const int wm = (w >> 1) * 64, wn = (w & 1) * 64;

  f32x4 acc[4][4];
#pragma unroll
  for (int i = 0; i < 4; ++i)
#pragma unroll
    for (int j = 0; j < 4; ++j) acc[i][j] = (f32x4){0.f, 0.f, 0.f, 0.f};

  int arow[2], aoff[2], bkp[2], bnq[2], bslot[2];
#pragma unroll
  for (int i = 0; i < 2; ++i) {
    int c = t + i * 256;
    arow[i] = c >> 2;
    aoff[i] = (c & 3) * 8;
    bkp[i] = c >> 5;
    bnq[i] = c & 31;
    bslot[i] = (((bkp[i] >> 2) ^ (bnq[i] & 3)) << 3) + (bkp[i] & 3) * 2;
  }

  uint4 pa[2];
  float4 pb0[2], pb1[2];
#pragma unroll
  for (int i = 0; i < 2; ++i) {  // prefetch k0 = k_lo
    pa[i] = *(const uint4*)&A[(size_t)(m0 + arow[i]) * K + k_lo + aoff[i]];
    const float* bp = B + (size_t)(k_lo + 2 * bkp[i]) * N + n0 + bnq[i] * 4;
    pb0[i] = *(const float4*)bp;
    pb1[i] = *(const float4*)(bp + N);
  }

  for (int k0 = k_lo; k0 < k_hi; k0 += 32) {
    __syncthreads();
#pragma unroll
    for (int i = 0; i < 2; ++i) {
      *(uint4*)&As[arow[i] * 40 + aoff[i]] = pa[i];
      int nq = bnq[i], so = bslot[i];
      *(u32*)&Bs[(nq * 4 + 0) * 40 + so] = pack2(pb0[i].x, pb1[i].x);
      *(u32*)&Bs[(nq * 4 + 1) * 40 + so] = pack2(pb0[i].y, pb1[i].y);
      *(u32*)&Bs[(nq * 4 + 2) * 40 + so] = pack2(pb0[i].z, pb1[i].z);
      *(u32*)&Bs[(nq * 4 + 3) * 40 + so] = pack2(pb0[i].w, pb1[i].w);
    }
    __syncthreads();
    if (k0 + 32 < k_hi) {
      int kn = k0 + 32;
#pragma unroll
      for (int i = 0; i < 2; ++i) {
        pa[i] = *(const uint4*)&A[(size_t)(m0 + arow[i]) * K + kn + aoff[i]];
        const float* bp = B + (size_t)(kn + 2 * bkp[i]) * N + n0 + bnq[i] * 4;
        pb0[i] = *(const float4*)bp;
        pb1[i] = *(const float4*)(bp + N);
      }
    }
    bf16x8 af[4], bfv[4];
#pragma unroll
    for (int mi = 0; mi < 4; ++mi)
      af[mi] = frag_ld(&As[(wm + mi * 16 + lr) * 40 + lg * 8]);
#pragma unroll
    for (int ni = 0; ni < 4; ++ni) {
      int cn = wn + ni * 16 + lr;
      bfv[ni] = frag_ld(&Bs[cn * 40 + ((lg ^ ((cn >> 2) & 3)) << 3)]);
    }
#pragma unroll
    for (int mi = 0; mi < 4; ++mi)
#pragma unroll
      for (int ni = 0; ni < 4; ++ni)
        acc[mi][ni] = MFMA(af[mi], bfv[ni], acc[mi][ni]);
  }

  if (EPI == 0) {
    // LDS-transposed epilogue: full-row float4 stores (no partial-line RFO)
    float* sm = (float*)smem4;  // [32][132] per mi-chunk
    for (int mi = 0; mi < 4; ++mi) {
      __syncthreads();
#pragma unroll
      for (int ni = 0; ni < 4; ++ni)
#pragma unroll
        for (int r = 0; r < 4; ++r)
          sm[((w >> 1) * 16 + lg * 4 + r) * 132 + wn + ni * 16 + lr] =
              acc[mi][ni][r];
      __syncthreads();
#pragma unroll
      for (int rr = 0; rr < 4; ++rr) {
        int lrow = (t >> 5) + rr * 8;
        int grow = m0 + (lrow >> 4) * 64 + mi * 16 + (lrow & 15);
        int coff = (t & 31) * 4;
        *(float4*)&((float*)Cv)[(size_t)grow * N + n0 + coff] =
            *(const float4*)&sm[lrow * 132 + coff];
      }
    }
  } else {
#pragma unroll
    for (int mi = 0; mi < 4; ++mi)
#pragma unroll
      for (int ni = 0; ni < 4; ++ni)
#pragma unroll
        for (int r = 0; r < 4; ++r) {
          int gm = m0 + wm + mi * 16 + lg * 4 + r;
          int gn = n0 + wn + ni * 16 + lr;
          size_t idx = (size_t)gm * N + gn;
          float v = acc[mi][ni][r];
          if (EPI == 1) ((u16*)Cv)[idx] = f2bf(v);
          else atomicAdd(&((float*)Cv)[idx], v);
        }
  }
}

// ---------------------------------------------------------------- fused FFN up+gate
// C[m][n] = silu(A@Bg) * (A@Bp), bf16 out. 128x64 tile, BK=32, grid (16, 64).
__global__ __launch_bounds__(256) void ffn_up_k(
    const u16* __restrict__ A, const float* __restrict__ Bg,
    const float* __restrict__ Bp, u16* __restrict__ C, int M, int N, int K) {
  const int m0 = blockIdx.x * 128, n0 = blockIdx.y * 64;
  __shared__ u16 As[128 * 40];
  __shared__ u16 Bgs[64 * 40];
  __shared__ u16 Bps[64 * 40];
  const int t = threadIdx.x;
  const int lane = t & 63, w = t >> 6;
  const int lr = lane & 15, lg = lane >> 4;
  const int wm = (w >> 1) * 64, wn = (w & 1) * 32;

  f32x4 ag[4][2], ap[4][2];
#pragma unroll
  for (int i = 0; i < 4; ++i)
#pragma unroll
    for (int j = 0; j < 2; ++j) {
      ag[i][j] = (f32x4){0.f, 0.f, 0.f, 0.f};
      ap[i][j] = (f32x4){0.f, 0.f, 0.f, 0.f};
    }

  int arow[2], aoff[2];
#pragma unroll
  for (int i = 0; i < 2; ++i) {
    int c = t + i * 256;
    arow[i] = c >> 2;
    aoff[i] = (c & 3) * 8;
  }
  const int kp = t >> 4, nq = t & 15;
  const int bslot = (((kp >> 2) ^ (nq & 3)) << 3) + (kp & 3) * 2;

  uint4 pa[2];
  float4 pg0, pg1, pq0, pq1;
#pragma unroll
  for (int i = 0; i < 2; ++i)
    pa[i] = *(const uint4*)&A[(size_t)(m0 + arow[i]) * K + aoff[i]];
  {
    const float* gp = Bg + (size_t)(2 * kp) * N + n0 + nq * 4;
    const float* qp = Bp + (size_t)(2 * kp) * N + n0 + nq * 4;
    pg0 = *(const float4*)gp;
    pg1 = *(const float4*)(gp + N);
    pq0 = *(const float4*)qp;
    pq1 = *(const float4*)(qp + N);
  }

  for (int k0 = 0; k0 < K; k0 += 32) {
    __syncthreads();
#pragma unroll
    for (int i = 0; i < 2; ++i) *(uint4*)&As[arow[i] * 40 + aoff[i]] = pa[i];
    *(u32*)&Bgs[(nq * 4 + 0) * 40 + bslot] = pack2(pg0.x, pg1.x);
    *(u32*)&Bgs[(nq * 4 + 1) * 40 + bslot] = pack2(pg0.y, pg1.y);
    *(u32*)&Bgs[(nq * 4 + 2) * 40 + bslot] = pack2(pg0.z, pg1.z);
    *(u32*)&Bgs[(nq * 4 + 3) * 40 + bslot] = pack2(pg0.w, pg1.w);
    *(u32*)&Bps[(nq * 4 + 0) * 40 + bslot] = pack2(pq0.x, pq1.x);
    *(u32*)&Bps[(nq * 4 + 1) * 40 + bslot] = pack2(pq0.y, pq1.y);
    *(u32*)&Bps[(nq * 4 + 2) * 40 + bslot] = pack2(pq0.z, pq1.z);
    *(u32*)&Bps[(nq * 4 + 3) * 40 + bslot] = pack2(pq0.w, pq1.w);
    __syncthreads();
    if (k0 + 32 < K) {
      int kn = k0 + 32;
#pragma unroll
      for (int i = 0; i < 2; ++i)
        pa[i] = *(const uint4*)&A[(size_t)(m0 + arow[i]) * K + kn + aoff[i]];
      const float* gp = Bg + (size_t)(kn + 2 * kp) * N + n0 + nq * 4;
      const float* qp = Bp + (size_t)(kn + 2 * kp) * N + n0 + nq * 4;
      pg0 = *(const float4*)gp;
      pg1 = *(const float4*)(gp + N);
      pq0 = *(const float4*)qp;
      pq1 = *(const float4*)(qp + N);
    }
    bf16x8 af[4], bg[2], bq[2];
#pragma unroll
    for (int mi = 0; mi < 4; ++mi)
      af[mi] = frag_ld(&As[(wm + mi * 16 + lr) * 40 + lg * 8]);
#pragma unroll
    for (int ni = 0; ni < 2; ++ni) {
      int cn = wn + ni * 16 + lr;
      int so = (lg ^ ((cn >> 2) & 3)) << 3;
      bg[ni] = frag_ld(&Bgs[cn * 40 + so]);
      bq[ni] = frag_ld(&Bps[cn * 40 + so]);
    }
#pragma unroll
    for (int mi = 0; mi < 4; ++mi)
#pragma unroll
      for (int ni = 0; ni < 2; ++ni) {
        ag[mi][ni] = MFMA(af[mi], bg[ni], ag[mi][ni]);
        ap[mi][ni] = MFMA(af[mi], bq[ni], ap[mi][ni]);
      }
  }

#pragma unroll
  for (int mi = 0; mi < 4; ++mi)
#pragma unroll
    for (int ni = 0; ni < 2; ++ni)
#pragma unroll
      for (int r = 0; r < 4; ++r) {
        int gm = m0 + wm + mi * 16 + lg * 4 + r;
        int gn = n0 + wn + ni * 16 + lr;
        float g = ag[mi][ni][r];
        float p = ap[mi][ni][r];
        C[(size_t)gm * N + gn] = f2bf((g / (1.f + __expf(-g))) * p);
      }
}

// ---------------------------------------------------------------- RoPE tables
__global__ __launch_bounds__(256) void ropetab_k(float2* __restrict__ tab) {
  int idx = blockIdx.x * 256 + threadIdx.x;  // 1024*32
  int i = idx & 31, l = idx >> 5;
  float inv_ts = exp2f((float)i * (-13.287712379549449f / 32.f));
  float sn, cs;
  sincosf((float)l * inv_ts, &sn, &cs);
  tab[idx] = make_float2(sn, cs);
}

// ---------------------------------------------------------------- RoPE (q scaled 1/8)
// in: [B][L][H][64] bf16; out: [B*H][L][64] bf16
__global__ __launch_bounds__(256) void rope_k(const u16* __restrict__ Qin,
                                              const u16* __restrict__ Kin,
                                              const float2* __restrict__ tab,
                                              u16* __restrict__ Qo,
                                              u16* __restrict__ Ko) {
  int idx = blockIdx.x * 256 + threadIdx.x;  // B*L*H*32 = 1048576
  int i = idx & 31;
  int h = (idx >> 5) & 15;
  int l = (idx >> 9) & 1023;
  int b = idx >> 19;
  float2 sc = tab[l * 32 + i];
  float sn = sc.x, cs = sc.y;
  size_t ib = (((size_t)b * 1024 + l) * 16 + h) * 64 + i;
  size_t ob = (((size_t)b * 16 + h) * 1024 + l) * 64 + i;
  float qf = bf2f(Qin[ib]), qs = bf2f(Qin[ib + 32]);
  Qo[ob] = f2bf((qf * cs - qs * sn) * 0.125f);
  Qo[ob + 32] = f2bf((qs * cs + qf * sn) * 0.125f);
  float kf = bf2f(Kin[ib]), ks = bf2f(Kin[ib + 32]);
  Ko[ob] = f2bf(kf * cs - ks * sn);
  Ko[ob + 32] = f2bf(ks * cs + kf * sn);
}

// ---------------------------------------------------------------- V transpose
// in: [B][L][H][64]; out: [B*H][64][L]
__global__ __launch_bounds__(256) void vtrans_k(const u16* __restrict__ Vin,
                                                u16* __restrict__ Vt) {
  int lt = blockIdx.x, bh = blockIdx.y;
  int b = bh >> 4, h = bh & 15;
  __shared__ u16 tile[64 * 72];
  int t = threadIdx.x;
#pragma unroll
  for (int i = 0; i < 2; ++i) {
    int c = t + i * 256;
    int row = c >> 3, off = c & 7;
    *(uint4*)&tile[row * 72 + off * 8] =
        *(const uint4*)&Vin[(((size_t)b * 1024 + lt * 64 + row) * 16 + h) * 64 + off * 8];
  }
  __syncthreads();
#pragma unroll
  for (int i = 0; i < 2; ++i) {
    int c = t + i * 256;
    int d = c >> 3, off = c & 7;
    u16x8 vv;
#pragma unroll
    for (int j = 0; j < 8; ++j) vv[j] = tile[(off * 8 + j) * 72 + d];
    *(uint4*)&Vt[((size_t)bh * 64 + d) * 1024 + lt * 64 + off * 8] =
        __builtin_bit_cast(uint4, vv);
  }
}

// ---------------------------------------------------------------- flash attention
// Q,K: [B*H][L][64] bf16 (Q pre-scaled), V: [B*H][64][L] bf16 -> O: [B][L][H][64] bf16
__global__ __launch_bounds__(256) void attn_k(const u16* __restrict__ Q,
                                              const u16* __restrict__ Kg,
                                              const u16* __restrict__ Vg,
                                              u16* __restrict__ O) {
  const int L = 1024;
  int qt = blockIdx.x, bh = blockIdx.y;
  int b = bh >> 4, h = bh & 15;
  __shared__ u16 Ks[64 * 72];  // [key][dim]
  __shared__ u16 Vs[64 * 72];  // [dim][key]
  __shared__ u16 Ps[64 * 72];  // [q][key] bf16
  __shared__ float Ss[64 * 65];
  __shared__ float mS[64], lS[64], aS[64];
  int t = threadIdx.x, w = t >> 6, lane = t & 63, lr = lane & 15, lg = lane >> 4;

  int qrow = qt * 64 + w * 16 + lr;
  const u16* qp = Q + ((size_t)bh * L + qrow) * 64;
  bf16x8 qa0 = frag_ld(qp + lg * 8);
  bf16x8 qa1 = frag_ld(qp + 32 + lg * 8);

  f32x4 o[4];
#pragma unroll
  for (int i = 0; i < 4; ++i) o[i] = (f32x4){0.f, 0.f, 0.f, 0.f};
  if (t < 64) { mS[t] = -3.0e38f; lS[t] = 0.f; }

  for (int kt = 0; kt <= qt; ++kt) {
    __syncthreads();
#pragma unroll
    for (int i = 0; i < 2; ++i) {
      int c = t + i * 256;
      int row = c >> 3, off = c & 7;
      *(uint4*)&Ks[row * 72 + off * 8] =
          *(const uint4*)&Kg[((size_t)bh * L + kt * 64 + row) * 64 + off * 8];
      *(uint4*)&Vs[row * 72 + off * 8] =
          *(const uint4*)&Vg[((size_t)bh * 64 + row) * L + kt * 64 + off * 8];
    }
    __syncthreads();
    f32x4 s[4];
#pragma unroll
    for (int ni = 0; ni < 4; ++ni) {
      bf16x8 b0 = frag_ld(&Ks[(ni * 16 + lr) * 72 + lg * 8]);
      bf16x8 b1 = frag_ld(&Ks[(ni * 16 + lr) * 72 + 32 + lg * 8]);
      f32x4 a = (f32x4){0.f, 0.f, 0.f, 0.f};
      a = MFMA(qa0, b0, a);
      a = MFMA(qa1, b1, a);
      s[ni] = a;
    }
#pragma unroll
    for (int ni = 0; ni < 4; ++ni)
#pragma unroll
      for (int r = 0; r < 4; ++r)
        Ss[(w * 16 + lg * 4 + r) * 65 + ni * 16 + lr] = s[ni][r];
    __syncthreads();
    {
      // wave-parallel online softmax: 4 lanes per q-row, 16 keys each
      int row = t >> 2, q4 = t & 3;
      int nv = (kt == qt) ? (row + 1) : 64;  // causal mask within diagonal tile
      float mold = mS[row];
      float mx = mold;
#pragma unroll
      for (int jj = 0; jj < 16; ++jj) {
        int j = q4 * 16 + jj;
        float sv = (j < nv) ? Ss[row * 65 + j] : -3.0e38f;
        mx = fmaxf(mx, sv);
      }
      mx = fmaxf(mx, __shfl_xor(mx, 1));
      mx = fmaxf(mx, __shfl_xor(mx, 2));
      float alpha = __expf(mold - mx);
      float sum = 0.f;
#pragma unroll
      for (int jj = 0; jj < 16; ++jj) {
        int j = q4 * 16 + jj;
        float p = (j < nv) ? __expf(Ss[row * 65 + j] - mx) : 0.f;
        sum += p;
        Ps[row * 72 + j] = f2bf(p);
      }
      sum += __shfl_xor(sum, 1);
      sum += __shfl_xor(sum, 2);
      if (q4 == 0) {
        mS[row] = mx;
        lS[row] = lS[row] * alpha + sum;
        aS[row] = alpha;
      }
    }
    __syncthreads();
    float al[4];
#pragma unroll
    for (int r = 0; r < 4; ++r) al[r] = aS[w * 16 + lg * 4 + r];
#pragma unroll
    for (int ni = 0; ni < 4; ++ni)
#pragma unroll
      for (int r = 0; r < 4; ++r) o[ni][r] *= al[r];
    bf16x8 pa0 = frag_ld(&Ps[(w * 16 + lr) * 72 + lg * 8]);
    bf16x8 pa1 = frag_ld(&Ps[(w * 16 + lr) * 72 + 32 + lg * 8]);
#pragma unroll
    for (int ni = 0; ni < 4; ++ni) {
      bf16x8 v0 = frag_ld(&Vs[(ni * 16 + lr) * 72 + lg * 8]);
      bf16x8 v1 = frag_ld(&Vs[(ni * 16 + lr) * 72 + 32 + lg * 8]);
      o[ni] = MFMA(pa0, v0, o[ni]);
      o[ni] = MFMA(pa1, v1, o[ni]);
    }
  }
#pragma unroll
  for (int r = 0; r < 4; ++r) {
    float linv = 1.f / lS[w * 16 + lg * 4 + r];
    int ql = qt * 64 + w * 16 + lg * 4 + r;
#pragma unroll
    for (int ni = 0; ni < 4; ++ni)
      O[(((size_t)b * 1024 + ql) * 16 + h) * 64 + ni * 16 + lr] =
          f2bf(o[ni][r] * linv);
  }
}

// ---------------------------------------------------------------- launch
extern "C" void kernel_launch(void* const* d_in, const int* in_sizes, int n_in,
                              void* d_out, int out_size, void* d_ws, size_t ws_size,
                              hipStream_t stream) {
  const int* tokens = (const int*)d_in[0];
  const float* embed = (const float*)d_in[1];
  const float* ln1 = (const float*)d_in[2];
  const float* Wq = (const float*)d_in[3];
  const float* Wk = (const float*)d_in[4];
  const float* Wv = (const float*)d_in[5];
  const float* Wo = (const float*)d_in[6];
  const float* ln2 = (const float*)d_in[7];
  const float* Wg = (const float*)d_in[8];
  const float* Wp = (const float*)d_in[9];
  const float* Wd = (const float*)d_in[10];
  const float* out_ln = (const float*)d_in[11];
  const float* head = (const float*)d_in[12];
  float* outp = (float*)d_out;

  char* ws = (char*)d_ws;
  const size_t MB = 1ull << 20;
  float* y = (float*)(ws + 0 * MB);    // 8 MB  residual (fp32)
  u16* xb = (u16*)(ws + 8 * MB);       // 4 MB  normed acts (bf16)
  u16* qb = (u16*)(ws + 12 * MB);      // 4 MB
  u16* kb = (u16*)(ws + 16 * MB);      // 4 MB
  u16* vb = (u16*)(ws + 20 * MB);      // 4 MB
  u16* Qr = (u16*)(ws + 24 * MB);      // 4 MB
  u16* Kr = (u16*)(ws + 28 * MB);      // 4 MB
  u16* Vt = (u16*)(ws + 32 * MB);      // 4 MB
  u16* ao = (u16*)(ws + 36 * MB);      // 4 MB
  float2* tab = (float2*)(ws + 40 * MB);  // 256 KB rope sin/cos
  u16* hb = (u16*)(ws + 72 * MB);      // 16 MB (total 88 MB)

  dim3 blk(256);
  embed_k<<<2048, blk, 0, stream>>>(tokens, embed, y);
  ropetab_k<<<128, blk, 0, stream>>>(tab);
  for (int l = 0; l < 8; ++l) {
    const float* wq = Wq + (size_t)l * 1024 * 1024;
    const float* wk = Wk + (size_t)l * 1024 * 1024;
    const float* wv = Wv + (size_t)l * 1024 * 1024;
    const float* wo = Wo + (size_t)l * 1024 * 1024;
    const float* wg = Wg + (size_t)l * 1024 * 4096;
    const float* wp = Wp + (size_t)l * 1024 * 4096;
    const float* wd = Wd + (size_t)l * 4096 * 1024;

    rmsnorm_k<<<2048, blk, 0, stream>>>(y, ln1 + l * 1024, xb);
    gemm_k<1><<<dim3(16, 8, 3), blk, 0, stream>>>(xb, wq, wk, wv, qb, kb, vb,
                                                  2048, 1024, 1024);
    rope_k<<<4096, blk, 0, stream>>>(qb, kb, tab, Qr, Kr);
    vtrans_k<<<dim3(16, 32), blk, 0, stream>>>(vb, Vt);
    attn_k<<<dim3(16, 32), blk, 0, stream>>>(Qr, Kr, Vt, ao);
    gemm_k<2><<<dim3(16, 8, 2), blk, 0, stream>>>(ao, wo, nullptr, nullptr, y,
                                                  nullptr, nullptr,
                                                  2048, 1024, 1024);
    rmsnorm_k<<<2048, blk, 0, stream>>>(y, ln2 + l * 1024, xb);
    ffn_up_k<<<dim3(16, 64), blk, 0, stream>>>(xb, wg, wp, hb, 2048, 4096, 1024);
    gemm_k<2><<<dim3(16, 8, 2), blk, 0, stream>>>(hb, wd, nullptr, nullptr, y,
                                                  nullptr, nullptr,
                                                  2048, 1024, 4096);
  }
  rmsnorm_k<<<2048, blk, 0, stream>>>(y, out_ln, xb);
  gemm_k<0><<<dim3(16, 250, 1), blk, 0, stream>>>(xb, head, nullptr, nullptr,
                                                  outp, nullptr, nullptr,
                                                  2048, 32000, 1024);
}